// Round 1
// baseline (392.369 us; speedup 1.0000x reference)
//
#include <hip/hip_runtime.h>
#include <math.h>

// Problem constants (match reference)
#define BB  32
#define SS  4096
#define VV  256
#define DD  256
#define CC  2
#define WIN 64
#define NW  64   // SS/WIN

// Workspace layout (float element offsets). Total 143360 floats = 573 KB.
#define WS_AT   0                    // At[t][s] = softmax-A[s][t]   (64*64)
#define WS_G    4096                 // g = emb @ W1^T               (256*256)
#define WS_W2T  (WS_G + VV*DD)       // W2t[d][c] = W2[c][d]         (256*256)
#define WS_POOL (WS_W2T + DD*DD)     // pooled sums [B][D]           (32*256)

__device__ __forceinline__ float fast_tanh(float v) {
  // tanh(x) = 1 - 2/(exp(2x)+1); stable for all x (exp->inf => 1, exp->0 => -1)
  float e = __expf(2.0f * v);
  return 1.0f - __fdividef(2.0f, e + 1.0f);
}

// ---------------------------------------------------------------------------
// Prep: block 0 -> attention matrix A (transposed), block 1 -> zero pooled,
// blocks [2, 2+V) -> g = emb @ W1^T, blocks [2+V, 2+V+D) -> W2 transpose.
// ---------------------------------------------------------------------------
__global__ __launch_bounds__(256) void prep_kernel(
    const float* __restrict__ emb, const float* __restrict__ W1,
    const float* __restrict__ W2, float* __restrict__ ws)
{
  const int blk = blockIdx.x;
  const int tid = threadIdx.x;
  float* At   = ws + WS_AT;
  float* g    = ws + WS_G;
  float* W2t  = ws + WS_W2T;
  float* pool = ws + WS_POOL;

  if (blk == 0) {
    // A[s,t] = softmax_t( cos(omega*(s-t)) ); same matrix for every window
    // since phases[n,s]-phases[n,t] depends only on s-t.
    if (tid < WIN) {
      const int s = tid;
      const float omega = 60.0f * 2.0f * 3.14159265358979323846f / 4095.0f;
      float row[WIN];
      float sum = 0.0f;
      for (int t = 0; t < WIN; ++t) {
        float e = expf(cosf(omega * (float)(s - t)));
        row[t] = e;
        sum += e;
      }
      const float inv = 1.0f / sum;
      for (int t = 0; t < WIN; ++t) At[t * WIN + s] = row[t] * inv;  // store transposed
    }
  } else if (blk == 1) {
    for (int i = tid; i < BB * DD; i += 256) pool[i] = 0.0f;
  } else if (blk < 2 + VV) {
    const int v = blk - 2;
    __shared__ float er[DD];
    er[tid] = emb[v * DD + tid];
    __syncthreads();
    const float* w = W1 + tid * DD;  // row d = tid of W1
    float acc = 0.0f;
    #pragma unroll 4
    for (int k = 0; k < DD; k += 4) {
      float4 wv = *(const float4*)(w + k);
      acc += er[k + 0] * wv.x + er[k + 1] * wv.y + er[k + 2] * wv.z + er[k + 3] * wv.w;
    }
    g[v * DD + tid] = acc;
  } else {
    const int d = blk - 2 - VV;          // 0..255
    W2t[d * DD + tid] = W2[tid * DD + d];
  }
}

// ---------------------------------------------------------------------------
// Main fused kernel: one block per (batch b, window n).
//   cv[s]   = g[x[b, n*64+s]][tid]                (register gather, coalesced)
//   h2[t,d] = tanh( sum_s At[t][s]*cv[s] + b1 )   (attention + layer1, in LDS)
//   z2[t,c] = sum_d h2[t][d] * W2t[d][c]          (register-tiled 16x4)
//   pool[b,c] += sum_t tanh(z2[t,c] + b2[c])
// ---------------------------------------------------------------------------
__global__ __launch_bounds__(256, 2) void main_kernel(
    const int*   __restrict__ x,   const float* __restrict__ g,
    const float* __restrict__ At,  const float* __restrict__ b1,
    const float* __restrict__ W2t, const float* __restrict__ b2,
    float* __restrict__ pool)
{
  __shared__ float h2[WIN][DD];   // 64 KiB -> 2 blocks/CU
  const int tid = threadIdx.x;
  const int b = blockIdx.x >> 6;
  const int n = blockIdx.x & 63;

  // --- gather: thread tid owns column tid of the 64 gathered g-rows ---
  const int* xw = x + b * SS + n * WIN;   // wave-uniform addresses -> s_load
  float cv[WIN];
  #pragma unroll
  for (int s = 0; s < WIN; ++s) {
    cv[s] = g[xw[s] * DD + tid];          // coalesced 1KB per s
  }
  const float b1v = b1[tid];

  // --- attention + tanh ---
  #pragma unroll 2
  for (int t = 0; t < WIN; ++t) {
    const float4* arow = (const float4*)(At + t * WIN);  // uniform -> scalar loads
    float z = 0.0f;
    #pragma unroll
    for (int s4 = 0; s4 < WIN / 4; ++s4) {
      float4 a = arow[s4];
      z += a.x * cv[4 * s4 + 0];
      z += a.y * cv[4 * s4 + 1];
      z += a.z * cv[4 * s4 + 2];
      z += a.w * cv[4 * s4 + 3];
    }
    h2[t][tid] = fast_tanh(z + b1v);
  }
  __syncthreads();

  // --- matmul2: thread -> cols 4*cg..4*cg+3, rows 16*tg..16*tg+15 ---
  const int cg = tid & 63;
  const int tg = tid >> 6;
  float acc[16][4];
  #pragma unroll
  for (int i = 0; i < 16; ++i)
    #pragma unroll
    for (int j = 0; j < 4; ++j) acc[i][j] = 0.0f;

  #pragma unroll 1
  for (int d0 = 0; d0 < DD; d0 += 4) {
    // coalesced: 64 lanes read 1KB contiguous per row of W2t
    float4 w0 = *(const float4*)(W2t + (d0 + 0) * DD + 4 * cg);
    float4 w1 = *(const float4*)(W2t + (d0 + 1) * DD + 4 * cg);
    float4 w2 = *(const float4*)(W2t + (d0 + 2) * DD + 4 * cg);
    float4 w3 = *(const float4*)(W2t + (d0 + 3) * DD + 4 * cg);
    #pragma unroll
    for (int i = 0; i < 16; ++i) {
      const int t = tg * 16 + i;
      float4 h = *(const float4*)(&h2[t][d0]);  // broadcast within wave
      acc[i][0] += h.x * w0.x + h.y * w1.x + h.z * w2.x + h.w * w3.x;
      acc[i][1] += h.x * w0.y + h.y * w1.y + h.z * w2.y + h.w * w3.y;
      acc[i][2] += h.x * w0.z + h.y * w1.z + h.z * w2.z + h.w * w3.z;
      acc[i][3] += h.x * w0.w + h.y * w1.w + h.z * w2.w + h.w * w3.w;
    }
  }
  __syncthreads();   // everyone done reading h2 before we reuse it

  // --- epilogue: tanh + pool over this block's 64 tokens ---
  float* partial = &h2[0][0];   // reuse LDS as partial[4][256]
  #pragma unroll
  for (int j = 0; j < 4; ++j) {
    const float b2v = b2[4 * cg + j];
    float s = 0.0f;
    #pragma unroll
    for (int i = 0; i < 16; ++i) s += fast_tanh(acc[i][j] + b2v);
    partial[tg * DD + 4 * cg + j] = s;
  }
  __syncthreads();
  const float v = partial[0 * DD + tid] + partial[1 * DD + tid] +
                  partial[2 * DD + tid] + partial[3 * DD + tid];
  atomicAdd(&pool[b * DD + tid], v);
}

// ---------------------------------------------------------------------------
// Final: out[b,c] = (pool[b,:] / S) . Wc[c,:] + bc[c]
// ---------------------------------------------------------------------------
__global__ __launch_bounds__(64) void final_kernel(
    const float* __restrict__ pool, const float* __restrict__ Wc,
    const float* __restrict__ bc, float* __restrict__ out)
{
  const int tid = threadIdx.x;
  if (tid < BB * CC) {
    const int b = tid / CC, c = tid % CC;
    const float* p = pool + b * DD;
    const float* w = Wc + c * DD;
    float acc = 0.0f;
    #pragma unroll 4
    for (int d = 0; d < DD; ++d) acc += p[d] * w[d];
    out[tid] = acc * (1.0f / 4096.0f) + bc[c];
  }
}

extern "C" void kernel_launch(void* const* d_in, const int* in_sizes, int n_in,
                              void* d_out, int out_size, void* d_ws, size_t ws_size,
                              hipStream_t stream) {
  const int*   x   = (const int*)  d_in[0];
  const float* emb = (const float*)d_in[1];
  const float* W1  = (const float*)d_in[2];
  const float* b1  = (const float*)d_in[3];
  const float* W2  = (const float*)d_in[4];
  const float* b2  = (const float*)d_in[5];
  const float* Wc  = (const float*)d_in[6];
  const float* bc  = (const float*)d_in[7];
  float* out = (float*)d_out;
  float* ws  = (float*)d_ws;

  prep_kernel<<<2 + VV + DD, 256, 0, stream>>>(emb, W1, W2, ws);
  main_kernel<<<BB * NW, 256, 0, stream>>>(x, ws + WS_G, ws + WS_AT, b1,
                                           ws + WS_W2T, b2, ws + WS_POOL);
  final_kernel<<<1, 64, 0, stream>>>(ws + WS_POOL, Wc, bc, out);
}

// Round 2
// 258.185 us; speedup vs baseline: 1.5197x; 1.5197x over previous
//
#include <hip/hip_runtime.h>
#include <hip/hip_bf16.h>
#include <math.h>

// Problem constants (match reference)
#define BB  32
#define SS  4096
#define VV  256
#define DD  256
#define CC  2
#define WIN 64
#define NW  64   // SS/WIN

// Workspace layout (byte offsets). Total 573440 B.
#define WS_AT_B    0u                         // float At[64][64]      (16384 B)
#define WS_G_B     16384u                     // float g[256][256]     (262144 B)
#define WS_W2HI_B  278528u                    // ushort W2hi[256][256] (131072 B)
#define WS_W2LO_B  409600u                    // ushort W2lo[256][256] (131072 B)
#define WS_POOL_B  540672u                    // float pool[32][256]   (32768 B)

typedef __attribute__((ext_vector_type(8))) short short8;   // 8 bf16 = 4 VGPRs
typedef __attribute__((ext_vector_type(4))) float f32x4;

__device__ __forceinline__ float fast_tanh(float v) {
  float e = __expf(2.0f * v);
  return 1.0f - __fdividef(2.0f, e + 1.0f);
}

__device__ __forceinline__ void split_bf16(float v, unsigned short& hi, unsigned short& lo) {
  __hip_bfloat16 h = __float2bfloat16(v);                    // RNE
  float r = v - __bfloat162float(h);
  __hip_bfloat16 l = __float2bfloat16(r);
  hi = *(unsigned short*)&h;
  lo = *(unsigned short*)&l;
}

// ---------------------------------------------------------------------------
// Prep: blk 0 -> attention matrix At (transposed), blk 1 -> zero pooled,
// blks [2, 2+V) -> g = emb @ W1^T, blks [2+V, 2+V+D) -> W2 split bf16 planes.
// ---------------------------------------------------------------------------
__global__ __launch_bounds__(256) void prep_kernel(
    const float* __restrict__ emb, const float* __restrict__ W1,
    const float* __restrict__ W2, char* __restrict__ ws)
{
  const int blk = blockIdx.x;
  const int tid = threadIdx.x;
  float*          At   = (float*)(ws + WS_AT_B);
  float*          g    = (float*)(ws + WS_G_B);
  unsigned short* W2hi = (unsigned short*)(ws + WS_W2HI_B);
  unsigned short* W2lo = (unsigned short*)(ws + WS_W2LO_B);
  float*          pool = (float*)(ws + WS_POOL_B);

  if (blk == 0) {
    // A[s,t] = softmax_t( cos(omega*(s-t)) ); identical for every window.
    if (tid < WIN) {
      const int s = tid;
      const float omega = 60.0f * 2.0f * 3.14159265358979323846f / 4095.0f;
      float row[WIN];
      float sum = 0.0f;
      for (int t = 0; t < WIN; ++t) {
        float e = expf(cosf(omega * (float)(s - t)));
        row[t] = e;
        sum += e;
      }
      const float inv = 1.0f / sum;
      for (int t = 0; t < WIN; ++t) At[t * WIN + s] = row[t] * inv;  // transposed
    }
  } else if (blk == 1) {
    for (int i = tid; i < BB * DD; i += 256) pool[i] = 0.0f;
  } else if (blk < 2 + VV) {
    const int v = blk - 2;
    __shared__ float er[DD];
    er[tid] = emb[v * DD + tid];
    __syncthreads();
    const float* w = W1 + tid * DD;
    float acc = 0.0f;
    #pragma unroll 4
    for (int k = 0; k < DD; k += 4) {
      float4 wv = *(const float4*)(w + k);
      acc += er[k + 0] * wv.x + er[k + 1] * wv.y + er[k + 2] * wv.z + er[k + 3] * wv.w;
    }
    g[v * DD + tid] = acc;
  } else {
    const int c = blk - 2 - VV;            // 0..255
    float wv = W2[c * DD + tid];
    unsigned short hi, lo;
    split_bf16(wv, hi, lo);
    W2hi[c * DD + tid] = hi;
    W2lo[c * DD + tid] = lo;
  }
}

// ---------------------------------------------------------------------------
// Main fused kernel: one block per (batch b, window n).
// Phase 1 (VALU fp32): gather g rows, attention + b1 + tanh -> split-bf16 LDS.
// Phase 2 (MFMA):      C2 = H2 @ W2^T via 16x16x32 bf16 with 3-product split.
// Epilogue: tanh(+b2), reduce over tokens, atomicAdd into pool.
// ---------------------------------------------------------------------------
#define LDP 264   // LDS row stride (elements): 256 + 8 pad -> bank-friendly b128

__global__ __launch_bounds__(256, 2) void main_kernel(
    const int*   __restrict__ x,    const float* __restrict__ g,
    const float* __restrict__ At,   const float* __restrict__ b1,
    const unsigned short* __restrict__ W2hi,
    const unsigned short* __restrict__ W2lo,
    const float* __restrict__ b2,   float* __restrict__ pool)
{
  __shared__ unsigned short Hhi[WIN][LDP];   // 33792 B
  __shared__ unsigned short Hlo[WIN][LDP];   // 33792 B  (total 66 KiB -> 2 blk/CU)
  const int tid = threadIdx.x;
  const int b = blockIdx.x >> 6;
  const int n = blockIdx.x & 63;

  // --- Phase 1: gather (thread owns column d = tid of the 64 gathered rows) ---
  const int* xw = x + b * SS + n * WIN;   // wave-uniform -> scalar loads
  float cv[WIN];
  #pragma unroll
  for (int s = 0; s < WIN; ++s) {
    cv[s] = g[xw[s] * DD + tid];          // coalesced 1KB per s
  }
  const float b1v = b1[tid];

  // attention + bias + tanh + split-bf16 store
  #pragma unroll 2
  for (int t = 0; t < WIN; ++t) {
    const float4* arow = (const float4*)(At + t * WIN);  // uniform -> scalar loads
    float z = 0.0f;
    #pragma unroll
    for (int s4 = 0; s4 < WIN / 4; ++s4) {
      float4 a = arow[s4];
      z += a.x * cv[4 * s4 + 0];
      z += a.y * cv[4 * s4 + 1];
      z += a.z * cv[4 * s4 + 2];
      z += a.w * cv[4 * s4 + 3];
    }
    float h = fast_tanh(z + b1v);
    unsigned short hi, lo;
    split_bf16(h, hi, lo);
    Hhi[t][tid] = hi;                     // 64 lanes x 2B contiguous: conflict-free
    Hlo[t][tid] = lo;
  }
  __syncthreads();

  // --- Phase 2: MFMA. wave w owns c in [64w, 64w+64); tiles: 4 mtiles x 4 ntiles
  const int lane = tid & 63;
  const int w    = tid >> 6;
  const int quad = lane >> 4;
  const int l16  = lane & 15;
  const int cbase = w * 64;

  f32x4 acc[4][4];
  #pragma unroll
  for (int mt = 0; mt < 4; ++mt)
    #pragma unroll
    for (int nt = 0; nt < 4; ++nt) acc[mt][nt] = (f32x4)0.0f;

  #pragma unroll 1
  for (int k0 = 0; k0 < DD; k0 += 32) {
    const int dd = k0 + quad * 8;         // this lane's 8-element K slice
    short8 ah[4], al[4], bh[4], bl[4];
    #pragma unroll
    for (int mt = 0; mt < 4; ++mt) {
      const int t = mt * 16 + l16;        // A[m=t][k=d]
      ah[mt] = *(const short8*)&Hhi[t][dd];   // ds_read_b128
      al[mt] = *(const short8*)&Hlo[t][dd];
    }
    #pragma unroll
    for (int nt = 0; nt < 4; ++nt) {
      const int c = cbase + nt * 16 + l16;    // B[k=d][n=c] = W2[c][d]
      bh[nt] = *(const short8*)(W2hi + c * DD + dd);  // global dwordx4
      bl[nt] = *(const short8*)(W2lo + c * DD + dd);
    }
    #pragma unroll
    for (int mt = 0; mt < 4; ++mt)
      #pragma unroll
      for (int nt = 0; nt < 4; ++nt) {
        acc[mt][nt] = __builtin_amdgcn_mfma_f32_16x16x32_bf16(ah[mt], bh[nt], acc[mt][nt], 0, 0, 0);
        acc[mt][nt] = __builtin_amdgcn_mfma_f32_16x16x32_bf16(ah[mt], bl[nt], acc[mt][nt], 0, 0, 0);
        acc[mt][nt] = __builtin_amdgcn_mfma_f32_16x16x32_bf16(al[mt], bh[nt], acc[mt][nt], 0, 0, 0);
      }
  }

  // --- Epilogue: tanh + token-sum. C elem: t = mt*16 + quad*4 + r, c = cbase+nt*16+l16.
  #pragma unroll
  for (int nt = 0; nt < 4; ++nt) {
    const int c = cbase + nt * 16 + l16;
    const float b2v = b2[c];
    float p = 0.0f;
    #pragma unroll
    for (int mt = 0; mt < 4; ++mt)
      #pragma unroll
      for (int r = 0; r < 4; ++r)
        p += fast_tanh(acc[mt][nt][r] + b2v);
    p += __shfl_xor(p, 16, 64);           // reduce across quads (different t)
    p += __shfl_xor(p, 32, 64);
    if (quad == 0) atomicAdd(&pool[b * DD + c], p);
  }
}

// ---------------------------------------------------------------------------
// Final: out[b,c] = (pool[b,:] / S) . Wc[c,:] + bc[c]
// ---------------------------------------------------------------------------
__global__ __launch_bounds__(64) void final_kernel(
    const float* __restrict__ pool, const float* __restrict__ Wc,
    const float* __restrict__ bc, float* __restrict__ out)
{
  const int tid = threadIdx.x;
  if (tid < BB * CC) {
    const int b = tid / CC, c = tid % CC;
    const float* p = pool + b * DD;
    const float* w = Wc + c * DD;
    float acc = 0.0f;
    #pragma unroll 4
    for (int d = 0; d < DD; ++d) acc += p[d] * w[d];
    out[tid] = acc * (1.0f / 4096.0f) + bc[c];
  }
}

extern "C" void kernel_launch(void* const* d_in, const int* in_sizes, int n_in,
                              void* d_out, int out_size, void* d_ws, size_t ws_size,
                              hipStream_t stream) {
  const int*   x   = (const int*)  d_in[0];
  const float* emb = (const float*)d_in[1];
  const float* W1  = (const float*)d_in[2];
  const float* b1  = (const float*)d_in[3];
  const float* W2  = (const float*)d_in[4];
  const float* b2  = (const float*)d_in[5];
  const float* Wc  = (const float*)d_in[6];
  const float* bc  = (const float*)d_in[7];
  float* out = (float*)d_out;
  char*  ws  = (char*)d_ws;

  prep_kernel<<<2 + VV + DD, 256, 0, stream>>>(emb, W1, W2, ws);
  main_kernel<<<BB * NW, 256, 0, stream>>>(
      x, (const float*)(ws + WS_G_B), (const float*)(ws + WS_AT_B), b1,
      (const unsigned short*)(ws + WS_W2HI_B), (const unsigned short*)(ws + WS_W2LO_B),
      b2, (float*)(ws + WS_POOL_B));
  final_kernel<<<1, 64, 0, stream>>>((const float*)(ws + WS_POOL_B), Wc, bc, out);
}

// Round 3
// 220.124 us; speedup vs baseline: 1.7825x; 1.1729x over previous
//
#include <hip/hip_runtime.h>
#include <hip/hip_bf16.h>
#include <math.h>

// Problem constants (match reference)
#define BB  32
#define SS  4096
#define VV  256
#define DD  256
#define CC  2
#define WIN 64
#define NW  64   // SS/WIN

typedef unsigned short ushort_t;
typedef unsigned int   uint_t;
typedef __attribute__((ext_vector_type(8))) short short8;    // 8 bf16 (4 VGPRs)
typedef __attribute__((ext_vector_type(4))) short short4v;   // 4 bf16 (2 VGPRs)
typedef __attribute__((ext_vector_type(4))) float f32x4;

// Workspace layout (byte offsets). Total 573440 B (same as R2's known-good size).
#define WS_ATHI_B 0u          // ushort Athi[64][64]   8192  (A-op layout: [t][s])
#define WS_ATLO_B 8192u       // ushort Atlo[64][64]   8192
#define WS_GPK_B  16384u      // uint   gpk[256][256]  262144 (hi<<16 | lo per elem)
#define WS_W2HI_B 278528u     // ushort W2hi[256][256] 131072
#define WS_W2LO_B 409600u     // ushort W2lo[256][256] 131072
#define WS_POOL_B 540672u     // float  pool[32][256]  32768

__device__ __forceinline__ float fast_tanh(float v) {
  float e = __expf(2.0f * v);
  return 1.0f - __fdividef(2.0f, e + 1.0f);
}

// Truncation-based bf16 split: v ~= hi + lo with |err| <= 2^-17 * |v|.
// Returns (hi_bits << 16) | lo_bits.
__device__ __forceinline__ uint_t split_pack(float v) {
  uint_t b  = __float_as_uint(v);
  uint_t hi = b & 0xffff0000u;
  float  r  = v - __uint_as_float(hi);
  uint_t lo = __float_as_uint(r) >> 16;
  return hi | lo;
}

// ---------------------------------------------------------------------------
// Prep grid (34 blocks):
//  blk 0       : attention matrix -> split bf16 planes Athi/Atlo ([t][s])
//  blk 1       : zero pooled accumulator
//  blk 2..17   : g = emb @ W1^T, 16 v-rows per block, packed-split into gpk
//  blk 18..33  : W2 -> split planes W2hi/W2lo, 16 c-rows per block
// ---------------------------------------------------------------------------
__global__ __launch_bounds__(256) void prep_kernel(
    const float* __restrict__ emb, const float* __restrict__ W1,
    const float* __restrict__ W2, char* __restrict__ ws)
{
  const int blk = blockIdx.x;
  const int tid = threadIdx.x;
  ushort_t* Athi = (ushort_t*)(ws + WS_ATHI_B);
  ushort_t* Atlo = (ushort_t*)(ws + WS_ATLO_B);
  uint_t*   gpk  = (uint_t*)  (ws + WS_GPK_B);
  ushort_t* W2hi = (ushort_t*)(ws + WS_W2HI_B);
  ushort_t* W2lo = (ushort_t*)(ws + WS_W2LO_B);
  float*    pool = (float*)   (ws + WS_POOL_B);

  if (blk == 0) {
    // A_mat[s,t] = softmax_t( cos(omega*(s-t)) ); identical for every window.
    // Store A-operand layout Aop[t][s] = A_mat[s][t], split bf16.
    if (tid < WIN) {
      const int s = tid;
      const float omega = 60.0f * 2.0f * 3.14159265358979323846f / 4095.0f;
      float row[WIN];
      float sum = 0.0f;
      for (int t = 0; t < WIN; ++t) {
        float e = expf(cosf(omega * (float)(s - t)));
        row[t] = e;
        sum += e;
      }
      const float inv = 1.0f / sum;
      for (int t = 0; t < WIN; ++t) {
        uint_t pk = split_pack(row[t] * inv);
        Athi[t * WIN + s] = (ushort_t)(pk >> 16);
        Atlo[t * WIN + s] = (ushort_t)(pk & 0xffffu);
      }
    }
  } else if (blk == 1) {
    for (int i = tid; i < BB * DD; i += 256) pool[i] = 0.0f;
  } else if (blk < 18) {
    // g rows v0..v0+15: thread tid computes column d=tid for all 16 rows.
    const int v0 = (blk - 2) * 16;
    __shared__ float er[16][DD];   // 16 KB
    for (int i = tid; i < 16 * DD; i += 256) er[i >> 8][i & 255] = emb[v0 * DD + i];
    __syncthreads();
    float acc[16];
    #pragma unroll
    for (int v = 0; v < 16; ++v) acc[v] = 0.0f;
    #pragma unroll 1
    for (int k0 = 0; k0 < DD; k0 += 64) {
      float4 wv[16];
      #pragma unroll
      for (int i = 0; i < 16; ++i) wv[i] = *(const float4*)(W1 + tid * DD + k0 + 4 * i);
      #pragma unroll
      for (int v = 0; v < 16; ++v) {
        float a = 0.0f;
        #pragma unroll
        for (int i = 0; i < 16; ++i) {
          float4 e = *(const float4*)(&er[v][k0 + 4 * i]);
          a += e.x * wv[i].x + e.y * wv[i].y + e.z * wv[i].z + e.w * wv[i].w;
        }
        acc[v] += a;
      }
    }
    #pragma unroll
    for (int v = 0; v < 16; ++v) gpk[(v0 + v) * DD + tid] = split_pack(acc[v]);
  } else {
    const int c0 = (blk - 18) * 16;
    #pragma unroll
    for (int i = 0; i < 16; ++i) {
      const int c = c0 + i;
      uint_t pk = split_pack(W2[c * DD + tid]);
      W2hi[c * DD + tid] = (ushort_t)(pk >> 16);
      W2lo[c * DD + tid] = (ushort_t)(pk & 0xffffu);
    }
  }
}

// ---------------------------------------------------------------------------
// Main fused kernel: one block per (batch b, window n). All matmuls on MFMA.
//  P1: gather g rows (packed u32) -> transposed split LDS Gt[d][s] (pad 68)
//  P2: attention MFMA: D1[t][d] = sum_s Aop[t][s] * Gt[d][s]   (3-product)
//  P3: tanh(+b1), split -> H2[t][d] LDS, chunk16 XOR-swizzled (conflict-free)
//  P4: matmul2 MFMA: D2[t][c] = sum_d H2[t][d] * W2[c][d]      (3-product)
//  P5: tanh(+b2), token-sum via shfl, atomicAdd into pool
// ---------------------------------------------------------------------------
#define GTP 68   // Gt row stride in shorts (136 B = 34 dwords == 2 mod 32)

__global__ __launch_bounds__(256, 2) void main_kernel(
    const int*      __restrict__ x,    const uint_t* __restrict__ gpk,
    const ushort_t* __restrict__ Athi, const ushort_t* __restrict__ Atlo,
    const float*    __restrict__ b1,
    const ushort_t* __restrict__ W2hi, const ushort_t* __restrict__ W2lo,
    const float*    __restrict__ b2,   float* __restrict__ pool)
{
  __shared__ char lds[69632];   // union: Gt planes (69632 B) / H2 planes (65536 B)
  ushort_t (*Gthi)[GTP] = (ushort_t(*)[GTP])(lds);
  ushort_t (*Gtlo)[GTP] = (ushort_t(*)[GTP])(lds + 34816);
  ushort_t (*H2hi)[DD]  = (ushort_t(*)[DD]) (lds);
  ushort_t (*H2lo)[DD]  = (ushort_t(*)[DD]) (lds + 32768);

  const int tid  = threadIdx.x;
  const int lane = tid & 63;
  const int w    = tid >> 6;
  const int quad = lane >> 4;
  const int l16  = lane & 15;
  const int b = blockIdx.x >> 6;
  const int n = blockIdx.x & 63;
  const int* xw = x + b * SS + n * WIN;   // wave-uniform -> scalar loads

  // --- P1: gather + transpose. Thread owns column d = tid of Gt. ---
  #pragma unroll 8
  for (int s2 = 0; s2 < WIN; s2 += 2) {
    uint_t p0 = gpk[xw[s2 + 0] * DD + tid];   // coalesced 1KB per s
    uint_t p1 = gpk[xw[s2 + 1] * DD + tid];
    uint_t hpk = (p0 >> 16) | (p1 & 0xffff0000u);   // shorts (s2, s2+1) hi plane
    uint_t lpk = (p0 & 0xffffu) | (p1 << 16);       // shorts (s2, s2+1) lo plane
    *(uint_t*)(&Gthi[tid][s2]) = hpk;   // bank = (2*tid + s2/2)%32 -> <=4-way
    *(uint_t*)(&Gtlo[tid][s2]) = lpk;
  }
  __syncthreads();

  // --- P2: attention MFMA. Wave w owns d in [64w, 64w+64). ---
  f32x4 acc1[4][4];
  #pragma unroll
  for (int mt = 0; mt < 4; ++mt)
    #pragma unroll
    for (int nt = 0; nt < 4; ++nt) acc1[mt][nt] = (f32x4)0.0f;

  const int dbase = w * 64;
  #pragma unroll
  for (int k0 = 0; k0 < WIN; k0 += 32) {
    const int sl = k0 + quad * 8;
    short8 ah[4], al[4], bh[4], bl[4];
    #pragma unroll
    for (int mt = 0; mt < 4; ++mt) {
      const int t = mt * 16 + l16;
      ah[mt] = *(const short8*)(Athi + t * WIN + sl);   // global dwordx4 (L1/L2)
      al[mt] = *(const short8*)(Atlo + t * WIN + sl);
    }
    #pragma unroll
    for (int nt = 0; nt < 4; ++nt) {
      const int d = dbase + nt * 16 + l16;
      short4v h0 = *(const short4v*)(&Gthi[d][sl]);     // ds_read_b64 (8B-aligned)
      short4v h1 = *(const short4v*)(&Gthi[d][sl + 4]);
      short4v g0 = *(const short4v*)(&Gtlo[d][sl]);
      short4v g1 = *(const short4v*)(&Gtlo[d][sl + 4]);
      bh[nt] = __builtin_shufflevector(h0, h1, 0, 1, 2, 3, 4, 5, 6, 7);
      bl[nt] = __builtin_shufflevector(g0, g1, 0, 1, 2, 3, 4, 5, 6, 7);
    }
    #pragma unroll
    for (int mt = 0; mt < 4; ++mt)
      #pragma unroll
      for (int nt = 0; nt < 4; ++nt) {
        acc1[mt][nt] = __builtin_amdgcn_mfma_f32_16x16x32_bf16(ah[mt], bh[nt], acc1[mt][nt], 0, 0, 0);
        acc1[mt][nt] = __builtin_amdgcn_mfma_f32_16x16x32_bf16(ah[mt], bl[nt], acc1[mt][nt], 0, 0, 0);
        acc1[mt][nt] = __builtin_amdgcn_mfma_f32_16x16x32_bf16(al[mt], bh[nt], acc1[mt][nt], 0, 0, 0);
      }
  }
  __syncthreads();   // Gt fully consumed; LDS will be rewritten as H2

  // --- P3: tanh(+b1), split, write H2 with chunk16 XOR swizzle. ---
  // C-layout: t = mt*16 + quad*4 + r, d = dbase + nt*16 + l16.
  #pragma unroll
  for (int nt = 0; nt < 4; ++nt) {
    const int d = dbase + nt * 16 + l16;
    const float b1v = b1[d];
    #pragma unroll
    for (int mt = 0; mt < 4; ++mt)
      #pragma unroll
      for (int r = 0; r < 4; ++r) {
        const int t = mt * 16 + quad * 4 + r;
        float h = fast_tanh(acc1[mt][nt][r] + b1v);
        uint_t pk = split_pack(h);
        const int col = (((d >> 3) ^ (t & 7)) << 3) + (d & 7);
        H2hi[t][col] = (ushort_t)(pk >> 16);
        H2lo[t][col] = (ushort_t)(pk & 0xffffu);
      }
  }
  __syncthreads();

  // --- P4: matmul2 MFMA. Wave w owns c in [64w, 64w+64). ---
  f32x4 acc2[4][4];
  #pragma unroll
  for (int mt = 0; mt < 4; ++mt)
    #pragma unroll
    for (int nt = 0; nt < 4; ++nt) acc2[mt][nt] = (f32x4)0.0f;

  const int cbase = w * 64;
  #pragma unroll 1
  for (int k0 = 0; k0 < DD; k0 += 32) {
    const int dsl = k0 + quad * 8;
    const int chunk = dsl >> 3;
    short8 ah[4], al[4], bh[4], bl[4];
    #pragma unroll
    for (int mt = 0; mt < 4; ++mt) {
      const int t = mt * 16 + l16;
      const int col = (chunk ^ (t & 7)) << 3;
      ah[mt] = *(const short8*)(&H2hi[t][col]);   // ds_read_b128, conflict-free
      al[mt] = *(const short8*)(&H2lo[t][col]);
    }
    #pragma unroll
    for (int nt = 0; nt < 4; ++nt) {
      const int c = cbase + nt * 16 + l16;
      bh[nt] = *(const short8*)(W2hi + c * DD + dsl);   // global dwordx4
      bl[nt] = *(const short8*)(W2lo + c * DD + dsl);
    }
    #pragma unroll
    for (int mt = 0; mt < 4; ++mt)
      #pragma unroll
      for (int nt = 0; nt < 4; ++nt) {
        acc2[mt][nt] = __builtin_amdgcn_mfma_f32_16x16x32_bf16(ah[mt], bh[nt], acc2[mt][nt], 0, 0, 0);
        acc2[mt][nt] = __builtin_amdgcn_mfma_f32_16x16x32_bf16(ah[mt], bl[nt], acc2[mt][nt], 0, 0, 0);
        acc2[mt][nt] = __builtin_amdgcn_mfma_f32_16x16x32_bf16(al[mt], bh[nt], acc2[mt][nt], 0, 0, 0);
      }
  }

  // --- P5: tanh(+b2) + token-sum. t = mt*16 + quad*4 + r, c = cbase+nt*16+l16.
  #pragma unroll
  for (int nt = 0; nt < 4; ++nt) {
    const int c = cbase + nt * 16 + l16;
    const float b2v = b2[c];
    float p = 0.0f;
    #pragma unroll
    for (int mt = 0; mt < 4; ++mt)
      #pragma unroll
      for (int r = 0; r < 4; ++r)
        p += fast_tanh(acc2[mt][nt][r] + b2v);
    p += __shfl_xor(p, 16, 64);   // sum across quads (different t only)
    p += __shfl_xor(p, 32, 64);
    if (quad == 0) atomicAdd(&pool[b * DD + c], p);
  }
}

// ---------------------------------------------------------------------------
// Final: out[b,c] = (pool[b,:] / S) . Wc[c,:] + bc[c]
// ---------------------------------------------------------------------------
__global__ __launch_bounds__(64) void final_kernel(
    const float* __restrict__ pool, const float* __restrict__ Wc,
    const float* __restrict__ bc, float* __restrict__ out)
{
  const int tid = threadIdx.x;
  if (tid < BB * CC) {
    const int b = tid / CC, c = tid % CC;
    const float* p = pool + b * DD;
    const float* wv = Wc + c * DD;
    float acc = 0.0f;
    #pragma unroll 4
    for (int d = 0; d < DD; ++d) acc += p[d] * wv[d];
    out[tid] = acc * (1.0f / 4096.0f) + bc[c];
  }
}

extern "C" void kernel_launch(void* const* d_in, const int* in_sizes, int n_in,
                              void* d_out, int out_size, void* d_ws, size_t ws_size,
                              hipStream_t stream) {
  const int*   x   = (const int*)  d_in[0];
  const float* emb = (const float*)d_in[1];
  const float* W1  = (const float*)d_in[2];
  const float* b1  = (const float*)d_in[3];
  const float* W2  = (const float*)d_in[4];
  const float* b2  = (const float*)d_in[5];
  const float* Wc  = (const float*)d_in[6];
  const float* bc  = (const float*)d_in[7];
  float* out = (float*)d_out;
  char*  ws  = (char*)d_ws;

  prep_kernel<<<34, 256, 0, stream>>>(emb, W1, W2, ws);
  main_kernel<<<BB * NW, 256, 0, stream>>>(
      x,
      (const uint_t*)  (ws + WS_GPK_B),
      (const ushort_t*)(ws + WS_ATHI_B), (const ushort_t*)(ws + WS_ATLO_B),
      b1,
      (const ushort_t*)(ws + WS_W2HI_B), (const ushort_t*)(ws + WS_W2LO_B),
      b2,
      (float*)(ws + WS_POOL_B));
  final_kernel<<<1, 64, 0, stream>>>((const float*)(ws + WS_POOL_B), Wc, bc, out);
}

// Round 4
// 216.047 us; speedup vs baseline: 1.8161x; 1.0189x over previous
//
#include <hip/hip_runtime.h>
#include <hip/hip_bf16.h>
#include <math.h>

// Problem constants (match reference)
#define BB  32
#define SS  4096
#define VV  256
#define DD  256
#define CC  2
#define WIN 64
#define NW  64   // SS/WIN

typedef unsigned short ushort_t;
typedef unsigned int   uint_t;
typedef __attribute__((ext_vector_type(8))) short short8;    // 8 bf16 (4 VGPRs)
typedef __attribute__((ext_vector_type(4))) float f32x4;

// Workspace layout (byte offsets). Total 573440 B.
#define WS_ATHI_B 0u          // ushort Athi[64][64]   8192  (A-op layout: [t][s])
#define WS_ATLO_B 8192u       // ushort Atlo[64][64]   8192
#define WS_GPK_B  16384u      // uint   gpk[256][256]  262144 (hi<<16 | lo per elem)
#define WS_W2HI_B 278528u     // ushort W2hi[256][256] 131072
#define WS_W2LO_B 409600u     // ushort W2lo[256][256] 131072
#define WS_POOL_B 540672u     // float  pool[32][256]  32768

__device__ __forceinline__ float fast_tanh(float v) {
  float e = __expf(2.0f * v);
  return 1.0f - __fdividef(2.0f, e + 1.0f);
}

// Truncation-based bf16 split: v ~= hi + lo with |err| <= 2^-17 * |v|.
// Returns (hi_bits << 16) | lo_bits.
__device__ __forceinline__ uint_t split_pack(float v) {
  uint_t b  = __float_as_uint(v);
  uint_t hi = b & 0xffff0000u;
  float  r  = v - __uint_as_float(hi);
  uint_t lo = __float_as_uint(r) >> 16;
  return hi | lo;
}

// Pack hi/lo halves of two packed u32 into bf16 pair dwords via v_perm.
// hi dword = [p0.hi16, p1.hi16] (p0 in low short), lo dword = [p0.lo16, p1.lo16].
__device__ __forceinline__ uint_t perm_hi(uint_t p0, uint_t p1) {
  return __builtin_amdgcn_perm(p1, p0, 0x07060302u);
}
__device__ __forceinline__ uint_t perm_lo(uint_t p0, uint_t p1) {
  return __builtin_amdgcn_perm(p1, p0, 0x05040100u);
}

union u4s8 { uint_t u[4]; short8 v; };

// ---------------------------------------------------------------------------
// Prep grid (34 blocks):
//  blk 0       : attention matrix -> split bf16 planes Athi/Atlo ([t][s])
//  blk 1       : zero pooled accumulator
//  blk 2..17   : g = emb @ W1^T, 16 v-rows per block, packed-split into gpk
//  blk 18..33  : W2 -> split planes W2hi/W2lo, 16 c-rows per block
// ---------------------------------------------------------------------------
__global__ __launch_bounds__(256) void prep_kernel(
    const float* __restrict__ emb, const float* __restrict__ W1,
    const float* __restrict__ W2, char* __restrict__ ws)
{
  const int blk = blockIdx.x;
  const int tid = threadIdx.x;
  ushort_t* Athi = (ushort_t*)(ws + WS_ATHI_B);
  ushort_t* Atlo = (ushort_t*)(ws + WS_ATLO_B);
  uint_t*   gpk  = (uint_t*)  (ws + WS_GPK_B);
  ushort_t* W2hi = (ushort_t*)(ws + WS_W2HI_B);
  ushort_t* W2lo = (ushort_t*)(ws + WS_W2LO_B);
  float*    pool = (float*)   (ws + WS_POOL_B);

  if (blk == 0) {
    // A_mat[s,t] = softmax_t( cos(omega*(s-t)) ); identical for every window.
    // Store A-operand layout Aop[t][s] = A_mat[s][t], split bf16.
    if (tid < WIN) {
      const int s = tid;
      const float omega = 60.0f * 2.0f * 3.14159265358979323846f / 4095.0f;
      float row[WIN];
      float sum = 0.0f;
      for (int t = 0; t < WIN; ++t) {
        float e = expf(cosf(omega * (float)(s - t)));
        row[t] = e;
        sum += e;
      }
      const float inv = 1.0f / sum;
      for (int t = 0; t < WIN; ++t) {
        uint_t pk = split_pack(row[t] * inv);
        Athi[t * WIN + s] = (ushort_t)(pk >> 16);
        Atlo[t * WIN + s] = (ushort_t)(pk & 0xffffu);
      }
    }
  } else if (blk == 1) {
    for (int i = tid; i < BB * DD; i += 256) pool[i] = 0.0f;
  } else if (blk < 18) {
    // g rows v0..v0+15: thread tid computes column d=tid for all 16 rows.
    const int v0 = (blk - 2) * 16;
    __shared__ float er[16][DD];   // 16 KB
    for (int i = tid; i < 16 * DD; i += 256) er[i >> 8][i & 255] = emb[v0 * DD + i];
    __syncthreads();
    float acc[16];
    #pragma unroll
    for (int v = 0; v < 16; ++v) acc[v] = 0.0f;
    #pragma unroll 1
    for (int k0 = 0; k0 < DD; k0 += 64) {
      float4 wv[16];
      #pragma unroll
      for (int i = 0; i < 16; ++i) wv[i] = *(const float4*)(W1 + tid * DD + k0 + 4 * i);
      #pragma unroll
      for (int v = 0; v < 16; ++v) {
        float a = 0.0f;
        #pragma unroll
        for (int i = 0; i < 16; ++i) {
          float4 e = *(const float4*)(&er[v][k0 + 4 * i]);
          a += e.x * wv[i].x + e.y * wv[i].y + e.z * wv[i].z + e.w * wv[i].w;
        }
        acc[v] += a;
      }
    }
    #pragma unroll
    for (int v = 0; v < 16; ++v) gpk[(v0 + v) * DD + tid] = split_pack(acc[v]);
  } else {
    const int c0 = (blk - 18) * 16;
    #pragma unroll
    for (int i = 0; i < 16; ++i) {
      const int c = c0 + i;
      uint_t pk = split_pack(W2[c * DD + tid]);
      W2hi[c * DD + tid] = (ushort_t)(pk >> 16);
      W2lo[c * DD + tid] = (ushort_t)(pk & 0xffffu);
    }
  }
}

// ---------------------------------------------------------------------------
// Main fused kernel: one block (512 thr, 8 waves) per (batch b, window n).
//  P2: gather gpk directly into B-frags (no LDS!), attention MFMA.
//      wave w owns d in [32w, 32w+32): acc1 = 4 mt (t) x 2 nt (d) tiles.
//  P3: tanh(+b1), split-pack -> H2 LDS (packed u32, swizzled cols).
//  [one __syncthreads]
//  P4: matmul2 MFMA: wave w owns c in [32w, 32w+32): 4 mt x 2 nt, K=256 (d).
//      A-frags from swizzled H2 (b128 pairs + v_perm unpack), B = W2 planes.
//  P5: tanh(+b2), token-sum via shfl, atomicAdd into pool.
// H2 swizzle: col = ((d>>3) ^ ((t>>2)&7))*8 + (d&7)  -> writes 2/bank (free),
// b128 reads evenly spread.
// ---------------------------------------------------------------------------
__global__ __launch_bounds__(512, 4) void main_kernel(
    const int*      __restrict__ x,    const uint_t* __restrict__ gpk,
    const ushort_t* __restrict__ Athi, const ushort_t* __restrict__ Atlo,
    const float*    __restrict__ b1,
    const ushort_t* __restrict__ W2hi, const ushort_t* __restrict__ W2lo,
    const float*    __restrict__ b2,   float* __restrict__ pool)
{
  __shared__ uint_t H2[WIN][DD];   // 64 KiB packed (hi<<16|lo), swizzled

  const int tid  = threadIdx.x;
  const int lane = tid & 63;
  const int w    = tid >> 6;       // 0..7
  const int quad = lane >> 4;
  const int l16  = lane & 15;
  const int b = blockIdx.x >> 6;
  const int n = blockIdx.x & 63;

  // Each lane holds x of token (n*64 + lane); rows fetched via shfl.
  const int xv = x[b * SS + n * WIN + lane];

  const int dbase = 32 * w;        // this wave's d-range for P2 (and c for P4)

  // --- P2: attention MFMA with direct-gather B-frags ---
  f32x4 acc1[4][2];
  #pragma unroll
  for (int mt = 0; mt < 4; ++mt)
    #pragma unroll
    for (int nt = 0; nt < 2; ++nt) acc1[mt][nt] = (f32x4)0.0f;

  #pragma unroll
  for (int k0 = 0; k0 < 2; ++k0) {
    const int sl = k0 * 32 + quad * 8;
    // A-frags (At, constant matrix, [t][s] layout -> contiguous dwordx4)
    short8 ah[4], al[4];
    #pragma unroll
    for (int mt = 0; mt < 4; ++mt) {
      const int t = mt * 16 + l16;
      ah[mt] = *(const short8*)(Athi + t * WIN + sl);
      al[mt] = *(const short8*)(Atlo + t * WIN + sl);
    }
    // Gather rows for this k-slice: 8 row indices via shfl, then per-nt loads.
    int xs[8];
    #pragma unroll
    for (int j = 0; j < 8; ++j) xs[j] = __shfl(xv, sl + j, 64);
    short8 bh[2], bl[2];
    #pragma unroll
    for (int nt = 0; nt < 2; ++nt) {
      const int d = dbase + 16 * nt + l16;
      uint_t q[8];
      #pragma unroll
      for (int j = 0; j < 8; ++j) q[j] = gpk[xs[j] * DD + d];  // 4x64B segments
      u4s8 h, l;
      #pragma unroll
      for (int p = 0; p < 4; ++p) {
        h.u[p] = perm_hi(q[2 * p], q[2 * p + 1]);
        l.u[p] = perm_lo(q[2 * p], q[2 * p + 1]);
      }
      bh[nt] = h.v;
      bl[nt] = l.v;
    }
    #pragma unroll
    for (int mt = 0; mt < 4; ++mt)
      #pragma unroll
      for (int nt = 0; nt < 2; ++nt) {
        acc1[mt][nt] = __builtin_amdgcn_mfma_f32_16x16x32_bf16(ah[mt], bh[nt], acc1[mt][nt], 0, 0, 0);
        acc1[mt][nt] = __builtin_amdgcn_mfma_f32_16x16x32_bf16(ah[mt], bl[nt], acc1[mt][nt], 0, 0, 0);
        acc1[mt][nt] = __builtin_amdgcn_mfma_f32_16x16x32_bf16(al[mt], bh[nt], acc1[mt][nt], 0, 0, 0);
      }
  }

  // --- P3: tanh(+b1), split, packed swizzled write (2 lanes/bank = free) ---
  #pragma unroll
  for (int nt = 0; nt < 2; ++nt) {
    const int d = dbase + 16 * nt + l16;
    const float b1v = b1[d];
    #pragma unroll
    for (int mt = 0; mt < 4; ++mt)
      #pragma unroll
      for (int r = 0; r < 4; ++r) {
        const int t = mt * 16 + quad * 4 + r;
        float h = fast_tanh(acc1[mt][nt][r] + b1v);
        const int col = (((d >> 3) ^ ((t >> 2) & 7)) << 3) + (d & 7);
        H2[t][col] = split_pack(h);
      }
  }
  __syncthreads();   // the only barrier

  // --- P4: matmul2 MFMA. Wave w owns c in [32w, 32w+32). ---
  f32x4 acc2[4][2];
  #pragma unroll
  for (int mt = 0; mt < 4; ++mt)
    #pragma unroll
    for (int nt = 0; nt < 2; ++nt) acc2[mt][nt] = (f32x4)0.0f;

  const int cbase = dbase;
  #pragma unroll 2
  for (int k0 = 0; k0 < 8; ++k0) {
    const int dsl = k0 * 32 + quad * 8;
    short8 ah[4], al[4], bh[2], bl[2];
    #pragma unroll
    for (int mt = 0; mt < 4; ++mt) {
      const int t = mt * 16 + l16;
      const int colu = ((4 * k0 + quad) ^ ((t >> 2) & 7)) << 3;
      const uint_t* src = &H2[t][colu];
      uint_t q[8];
      *(uint4*)(q)     = *(const uint4*)(src);       // ds_read_b128
      *(uint4*)(q + 4) = *(const uint4*)(src + 4);   // ds_read_b128
      u4s8 h, l;
      #pragma unroll
      for (int p = 0; p < 4; ++p) {
        h.u[p] = perm_hi(q[2 * p], q[2 * p + 1]);
        l.u[p] = perm_lo(q[2 * p], q[2 * p + 1]);
      }
      ah[mt] = h.v;
      al[mt] = l.v;
    }
    #pragma unroll
    for (int nt = 0; nt < 2; ++nt) {
      const int c = cbase + 16 * nt + l16;
      bh[nt] = *(const short8*)(W2hi + c * DD + dsl);   // global dwordx4 (L2)
      bl[nt] = *(const short8*)(W2lo + c * DD + dsl);
    }
    #pragma unroll
    for (int mt = 0; mt < 4; ++mt)
      #pragma unroll
      for (int nt = 0; nt < 2; ++nt) {
        acc2[mt][nt] = __builtin_amdgcn_mfma_f32_16x16x32_bf16(ah[mt], bh[nt], acc2[mt][nt], 0, 0, 0);
        acc2[mt][nt] = __builtin_amdgcn_mfma_f32_16x16x32_bf16(ah[mt], bl[nt], acc2[mt][nt], 0, 0, 0);
        acc2[mt][nt] = __builtin_amdgcn_mfma_f32_16x16x32_bf16(al[mt], bh[nt], acc2[mt][nt], 0, 0, 0);
      }
  }

  // --- P5: tanh(+b2) + token-sum. t = mt*16 + quad*4 + r, c = cbase+16nt+l16.
  #pragma unroll
  for (int nt = 0; nt < 2; ++nt) {
    const int c = cbase + 16 * nt + l16;
    const float b2v = b2[c];
    float p = 0.0f;
    #pragma unroll
    for (int mt = 0; mt < 4; ++mt)
      #pragma unroll
      for (int r = 0; r < 4; ++r)
        p += fast_tanh(acc2[mt][nt][r] + b2v);
    p += __shfl_xor(p, 16, 64);   // sum across quads (different t only)
    p += __shfl_xor(p, 32, 64);
    if (quad == 0) atomicAdd(&pool[b * DD + c], p);
  }
}

// ---------------------------------------------------------------------------
// Final: out[b,c] = (pool[b,:] / S) . Wc[c,:] + bc[c]
// ---------------------------------------------------------------------------
__global__ __launch_bounds__(64) void final_kernel(
    const float* __restrict__ pool, const float* __restrict__ Wc,
    const float* __restrict__ bc, float* __restrict__ out)
{
  const int tid = threadIdx.x;
  if (tid < BB * CC) {
    const int b = tid / CC, c = tid % CC;
    const float* p = pool + b * DD;
    const float* wv = Wc + c * DD;
    float acc = 0.0f;
    #pragma unroll 4
    for (int d = 0; d < DD; ++d) acc += p[d] * wv[d];
    out[tid] = acc * (1.0f / 4096.0f) + bc[c];
  }
}

extern "C" void kernel_launch(void* const* d_in, const int* in_sizes, int n_in,
                              void* d_out, int out_size, void* d_ws, size_t ws_size,
                              hipStream_t stream) {
  const int*   x   = (const int*)  d_in[0];
  const float* emb = (const float*)d_in[1];
  const float* W1  = (const float*)d_in[2];
  const float* b1  = (const float*)d_in[3];
  const float* W2  = (const float*)d_in[4];
  const float* b2  = (const float*)d_in[5];
  const float* Wc  = (const float*)d_in[6];
  const float* bc  = (const float*)d_in[7];
  float* out = (float*)d_out;
  char*  ws  = (char*)d_ws;

  prep_kernel<<<34, 256, 0, stream>>>(emb, W1, W2, ws);
  main_kernel<<<BB * NW, 512, 0, stream>>>(
      x,
      (const uint_t*)  (ws + WS_GPK_B),
      (const ushort_t*)(ws + WS_ATHI_B), (const ushort_t*)(ws + WS_ATLO_B),
      b1,
      (const ushort_t*)(ws + WS_W2HI_B), (const ushort_t*)(ws + WS_W2LO_B),
      b2,
      (float*)(ws + WS_POOL_B));
  final_kernel<<<1, 64, 0, stream>>>((const float*)(ws + WS_POOL_B), Wc, bc, out);
}

// Round 5
// 193.866 us; speedup vs baseline: 2.0239x; 1.1144x over previous
//
#include <hip/hip_runtime.h>
#include <hip/hip_bf16.h>
#include <math.h>

// Problem constants (match reference)
#define BB  32
#define SS  4096
#define VV  256
#define DD  256
#define CC  2
#define WIN 64
#define NW  64   // SS/WIN

typedef unsigned short ushort_t;
typedef unsigned int   uint_t;
typedef __attribute__((ext_vector_type(8))) short short8;    // 8 bf16 (4 VGPRs)
typedef __attribute__((ext_vector_type(4))) float f32x4;

// Workspace layout (byte offsets). Total 573440 B.
#define WS_ATHI_B 0u          // ushort Athi[64][64]   8192  (A-op layout: [t][s])
#define WS_ATLO_B 8192u       // ushort Atlo[64][64]   8192
#define WS_GPK_B  16384u      // uint   gpk[256][256]  262144 (hi<<16 | lo per elem)
#define WS_W2HI_B 278528u     // ushort W2hi[256][256] 131072
#define WS_W2LO_B 409600u     // ushort W2lo[256][256] 131072
#define WS_POOL_B 540672u     // float  pool[32][256]  32768

__device__ __forceinline__ float fast_tanh(float v) {
  float e = __expf(2.0f * v);
  return 1.0f - __fdividef(2.0f, e + 1.0f);
}

// Truncation-based bf16 split: v ~= hi + lo with |err| <= 2^-17 * |v|.
// Returns (hi_bits << 16) | lo_bits.
__device__ __forceinline__ uint_t split_pack(float v) {
  uint_t b  = __float_as_uint(v);
  uint_t hi = b & 0xffff0000u;
  float  r  = v - __uint_as_float(hi);
  uint_t lo = __float_as_uint(r) >> 16;
  return hi | lo;
}

// Pack hi/lo halves of two packed u32 into bf16 pair dwords via v_perm.
__device__ __forceinline__ uint_t perm_hi(uint_t p0, uint_t p1) {
  return __builtin_amdgcn_perm(p1, p0, 0x07060302u);
}
__device__ __forceinline__ uint_t perm_lo(uint_t p0, uint_t p1) {
  return __builtin_amdgcn_perm(p1, p0, 0x05040100u);
}

union u4s8 { uint_t u[4]; short8 v; };

// ---------------------------------------------------------------------------
// Prep grid (130 blocks):
//  blk 0       : attention matrix -> split bf16 planes Athi/Atlo ([t][s])
//  blk 1       : zero pooled accumulator
//  blk 2..65   : g = emb @ W1^T, 4 v-rows per block, packed-split into gpk
//  blk 66..129 : W2 -> split planes W2hi/W2lo, 4 c-rows per block
// ---------------------------------------------------------------------------
__global__ __launch_bounds__(256) void prep_kernel(
    const float* __restrict__ emb, const float* __restrict__ W1,
    const float* __restrict__ W2, char* __restrict__ ws)
{
  const int blk = blockIdx.x;
  const int tid = threadIdx.x;
  ushort_t* Athi = (ushort_t*)(ws + WS_ATHI_B);
  ushort_t* Atlo = (ushort_t*)(ws + WS_ATLO_B);
  uint_t*   gpk  = (uint_t*)  (ws + WS_GPK_B);
  ushort_t* W2hi = (ushort_t*)(ws + WS_W2HI_B);
  ushort_t* W2lo = (ushort_t*)(ws + WS_W2LO_B);
  float*    pool = (float*)   (ws + WS_POOL_B);

  if (blk == 0) {
    // A_mat[s,t] = softmax_t( cos(omega*(s-t)) ); identical for every window.
    // Store A-operand layout Aop[t][s] = A_mat[s][t], split bf16.
    if (tid < WIN) {
      const int s = tid;
      const float omega = 60.0f * 2.0f * 3.14159265358979323846f / 4095.0f;
      float row[WIN];
      float sum = 0.0f;
      for (int t = 0; t < WIN; ++t) {
        float e = expf(cosf(omega * (float)(s - t)));
        row[t] = e;
        sum += e;
      }
      const float inv = 1.0f / sum;
      for (int t = 0; t < WIN; ++t) {
        uint_t pk = split_pack(row[t] * inv);
        Athi[t * WIN + s] = (ushort_t)(pk >> 16);
        Atlo[t * WIN + s] = (ushort_t)(pk & 0xffffu);
      }
    }
  } else if (blk == 1) {
    for (int i = tid; i < BB * DD; i += 256) pool[i] = 0.0f;
  } else if (blk < 66) {
    // g rows v0..v0+3: thread tid computes column d=tid for all 4 rows.
    const int v0 = (blk - 2) * 4;
    __shared__ float er[4][DD];   // 4 KB
    for (int i = tid; i < 4 * DD; i += 256) er[i >> 8][i & 255] = emb[v0 * DD + i];
    __syncthreads();
    float acc[4] = {0.0f, 0.0f, 0.0f, 0.0f};
    #pragma unroll 1
    for (int k0 = 0; k0 < DD; k0 += 64) {
      float4 wv[16];
      #pragma unroll
      for (int i = 0; i < 16; ++i) wv[i] = *(const float4*)(W1 + tid * DD + k0 + 4 * i);
      #pragma unroll
      for (int v = 0; v < 4; ++v) {
        float a = 0.0f;
        #pragma unroll
        for (int i = 0; i < 16; ++i) {
          float4 e = *(const float4*)(&er[v][k0 + 4 * i]);
          a += e.x * wv[i].x + e.y * wv[i].y + e.z * wv[i].z + e.w * wv[i].w;
        }
        acc[v] += a;
      }
    }
    #pragma unroll
    for (int v = 0; v < 4; ++v) gpk[(v0 + v) * DD + tid] = split_pack(acc[v]);
  } else {
    const int c0 = (blk - 66) * 4;
    #pragma unroll
    for (int i = 0; i < 4; ++i) {
      const int c = c0 + i;
      uint_t pk = split_pack(W2[c * DD + tid]);
      W2hi[c * DD + tid] = (ushort_t)(pk >> 16);
      W2lo[c * DD + tid] = (ushort_t)(pk & 0xffffu);
    }
  }
}

// ---------------------------------------------------------------------------
// Main fused kernel: one block (512 thr, 8 waves) per (batch b, window n).
//  P2: gather gpk directly into B-frags (no LDS), attention MFMA.
//      wave w owns d in [32w, 32w+32): acc1 = 4 mt (t) x 2 nt (d) tiles.
//  P3: tanh(+b1), split-pack -> H2 LDS (packed u32, rotation layout).
//  [one __syncthreads]
//  P4: matmul2 MFMA: wave w owns c in [32w, 32w+32): 4 mt x 2 nt, K=256 (d).
//      A-frags from H2 (2x ds_read_b128 + v_perm unpack), B = W2 planes.
//  P5: tanh(+b2), token-sum via shfl, atomicAdd into pool.
//
// H2 rotation layout: H2[t][p], p = (d + 4*t) & 255.
//  Read  (t=mt*16+l16, dbase=32k0+8quad): bank = (8quad+4l16)%32 -> each
//    4-bank group gets 8 lanes x 4 dwords = 8 dwords/bank = 8-phase minimum:
//    conflict-free. 16B alignment preserved (dbase%8==0).
//  Write (d=dbase+16nt+l16, t=mt*16+quad*4+r): bank=(16(nt+quad)+l16+4r)%32
//    -> exactly 2 lanes/bank = free (m136).
// ---------------------------------------------------------------------------
__global__ __launch_bounds__(512, 4) void main_kernel(
    const int*      __restrict__ x,    const uint_t* __restrict__ gpk,
    const ushort_t* __restrict__ Athi, const ushort_t* __restrict__ Atlo,
    const float*    __restrict__ b1,
    const ushort_t* __restrict__ W2hi, const ushort_t* __restrict__ W2lo,
    const float*    __restrict__ b2,   float* __restrict__ pool)
{
  __shared__ uint_t H2[WIN][DD];   // 64 KiB packed (hi<<16|lo), rotation layout

  const int tid  = threadIdx.x;
  const int lane = tid & 63;
  const int w    = tid >> 6;       // 0..7
  const int quad = lane >> 4;
  const int l16  = lane & 15;
  const int b = blockIdx.x >> 6;
  const int n = blockIdx.x & 63;

  // Each lane holds x of token (n*64 + lane); rows fetched via shfl.
  const int xv = x[b * SS + n * WIN + lane];

  const int dbase = 32 * w;        // this wave's d-range for P2 (and c for P4)

  // --- P2: attention MFMA with direct-gather B-frags ---
  f32x4 acc1[4][2];
  #pragma unroll
  for (int mt = 0; mt < 4; ++mt)
    #pragma unroll
    for (int nt = 0; nt < 2; ++nt) acc1[mt][nt] = (f32x4)0.0f;

  #pragma unroll
  for (int k0 = 0; k0 < 2; ++k0) {
    const int sl = k0 * 32 + quad * 8;
    // A-frags (At, constant matrix, [t][s] layout -> contiguous dwordx4)
    short8 ah[4], al[4];
    #pragma unroll
    for (int mt = 0; mt < 4; ++mt) {
      const int t = mt * 16 + l16;
      ah[mt] = *(const short8*)(Athi + t * WIN + sl);
      al[mt] = *(const short8*)(Atlo + t * WIN + sl);
    }
    // Gather rows for this k-slice: 8 row indices via shfl, then per-nt loads.
    int xs[8];
    #pragma unroll
    for (int j = 0; j < 8; ++j) xs[j] = __shfl(xv, sl + j, 64);
    short8 bh[2], bl[2];
    #pragma unroll
    for (int nt = 0; nt < 2; ++nt) {
      const int d = dbase + 16 * nt + l16;
      uint_t q[8];
      #pragma unroll
      for (int j = 0; j < 8; ++j) q[j] = gpk[xs[j] * DD + d];  // 4x64B segments
      u4s8 h, l;
      #pragma unroll
      for (int p = 0; p < 4; ++p) {
        h.u[p] = perm_hi(q[2 * p], q[2 * p + 1]);
        l.u[p] = perm_lo(q[2 * p], q[2 * p + 1]);
      }
      bh[nt] = h.v;
      bl[nt] = l.v;
    }
    #pragma unroll
    for (int mt = 0; mt < 4; ++mt)
      #pragma unroll
      for (int nt = 0; nt < 2; ++nt) {
        acc1[mt][nt] = __builtin_amdgcn_mfma_f32_16x16x32_bf16(ah[mt], bh[nt], acc1[mt][nt], 0, 0, 0);
        acc1[mt][nt] = __builtin_amdgcn_mfma_f32_16x16x32_bf16(ah[mt], bl[nt], acc1[mt][nt], 0, 0, 0);
        acc1[mt][nt] = __builtin_amdgcn_mfma_f32_16x16x32_bf16(al[mt], bh[nt], acc1[mt][nt], 0, 0, 0);
      }
  }

  // --- P3: tanh(+b1), split, packed rotated write (2 lanes/bank = free) ---
  #pragma unroll
  for (int nt = 0; nt < 2; ++nt) {
    const int d = dbase + 16 * nt + l16;
    const float b1v = b1[d];
    #pragma unroll
    for (int mt = 0; mt < 4; ++mt)
      #pragma unroll
      for (int r = 0; r < 4; ++r) {
        const int t = mt * 16 + quad * 4 + r;
        float h = fast_tanh(acc1[mt][nt][r] + b1v);
        H2[t][(d + 4 * t) & 255] = split_pack(h);
      }
  }
  __syncthreads();   // the only barrier

  // --- P4: matmul2 MFMA. Wave w owns c in [32w, 32w+32). ---
  f32x4 acc2[4][2];
  #pragma unroll
  for (int mt = 0; mt < 4; ++mt)
    #pragma unroll
    for (int nt = 0; nt < 2; ++nt) acc2[mt][nt] = (f32x4)0.0f;

  const int cbase = dbase;
  #pragma unroll 2
  for (int k0 = 0; k0 < 8; ++k0) {
    const int dsl = k0 * 32 + quad * 8;   // d element base for this lane
    short8 ah[4], al[4], bh[2], bl[2];
    #pragma unroll
    for (int mt = 0; mt < 4; ++mt) {
      const int t = mt * 16 + l16;
      const uint_t* row = &H2[t][0];
      const int p0 = (dsl + 4 * t) & 255;       // multiple of 4 -> 16B aligned
      const int p4 = (dsl + 4 + 4 * t) & 255;
      uint_t q[8];
      *(uint4*)(q)     = *(const uint4*)(row + p0);   // ds_read_b128
      *(uint4*)(q + 4) = *(const uint4*)(row + p4);   // ds_read_b128
      u4s8 h, l;
      #pragma unroll
      for (int p = 0; p < 4; ++p) {
        h.u[p] = perm_hi(q[2 * p], q[2 * p + 1]);
        l.u[p] = perm_lo(q[2 * p], q[2 * p + 1]);
      }
      ah[mt] = h.v;
      al[mt] = l.v;
    }
    #pragma unroll
    for (int nt = 0; nt < 2; ++nt) {
      const int c = cbase + 16 * nt + l16;
      bh[nt] = *(const short8*)(W2hi + c * DD + dsl);   // global dwordx4 (L2)
      bl[nt] = *(const short8*)(W2lo + c * DD + dsl);
    }
    #pragma unroll
    for (int mt = 0; mt < 4; ++mt)
      #pragma unroll
      for (int nt = 0; nt < 2; ++nt) {
        acc2[mt][nt] = __builtin_amdgcn_mfma_f32_16x16x32_bf16(ah[mt], bh[nt], acc2[mt][nt], 0, 0, 0);
        acc2[mt][nt] = __builtin_amdgcn_mfma_f32_16x16x32_bf16(ah[mt], bl[nt], acc2[mt][nt], 0, 0, 0);
        acc2[mt][nt] = __builtin_amdgcn_mfma_f32_16x16x32_bf16(al[mt], bh[nt], acc2[mt][nt], 0, 0, 0);
      }
  }

  // --- P5: tanh(+b2) + token-sum. t = mt*16 + quad*4 + r, c = cbase+16nt+l16.
  #pragma unroll
  for (int nt = 0; nt < 2; ++nt) {
    const int c = cbase + 16 * nt + l16;
    const float b2v = b2[c];
    float p = 0.0f;
    #pragma unroll
    for (int mt = 0; mt < 4; ++mt)
      #pragma unroll
      for (int r = 0; r < 4; ++r)
        p += fast_tanh(acc2[mt][nt][r] + b2v);
    p += __shfl_xor(p, 16, 64);   // sum across quads (different t only)
    p += __shfl_xor(p, 32, 64);
    if (quad == 0) atomicAdd(&pool[b * DD + c], p);
  }
}

// ---------------------------------------------------------------------------
// Final: out[b,c] = (pool[b,:] / S) . Wc[c,:] + bc[c]
// ---------------------------------------------------------------------------
__global__ __launch_bounds__(64) void final_kernel(
    const float* __restrict__ pool, const float* __restrict__ Wc,
    const float* __restrict__ bc, float* __restrict__ out)
{
  const int tid = threadIdx.x;
  if (tid < BB * CC) {
    const int b = tid / CC, c = tid % CC;
    const float* p = pool + b * DD;
    const float* wv = Wc + c * DD;
    float acc = 0.0f;
    #pragma unroll 4
    for (int d = 0; d < DD; ++d) acc += p[d] * wv[d];
    out[tid] = acc * (1.0f / 4096.0f) + bc[c];
  }
}

extern "C" void kernel_launch(void* const* d_in, const int* in_sizes, int n_in,
                              void* d_out, int out_size, void* d_ws, size_t ws_size,
                              hipStream_t stream) {
  const int*   x   = (const int*)  d_in[0];
  const float* emb = (const float*)d_in[1];
  const float* W1  = (const float*)d_in[2];
  const float* b1  = (const float*)d_in[3];
  const float* W2  = (const float*)d_in[4];
  const float* b2  = (const float*)d_in[5];
  const float* Wc  = (const float*)d_in[6];
  const float* bc  = (const float*)d_in[7];
  float* out = (float*)d_out;
  char*  ws  = (char*)d_ws;

  prep_kernel<<<130, 256, 0, stream>>>(emb, W1, W2, ws);
  main_kernel<<<BB * NW, 512, 0, stream>>>(
      x,
      (const uint_t*)  (ws + WS_GPK_B),
      (const ushort_t*)(ws + WS_ATHI_B), (const ushort_t*)(ws + WS_ATLO_B),
      b1,
      (const ushort_t*)(ws + WS_W2HI_B), (const ushort_t*)(ws + WS_W2LO_B),
      b2,
      (float*)(ws + WS_POOL_B));
  final_kernel<<<1, 64, 0, stream>>>((const float*)(ws + WS_POOL_B), Wc, bc, out);
}